// Round 12
// baseline (245.249 us; speedup 1.0000x reference)
//
#include <hip/hip_runtime.h>
#include <stdint.h>

#define B_N   8192
#define D_K   626
#define KPAD  640        // fp8 bytes per row (padded)
#define BK    128        // K-bytes per step
#define KSTEPS 5         // KPAD / BK
#define BM    128
#define BN    128
#define COL_CHUNKS 16
#define TILES_PER_CHUNK 4   // 8192 / (16*128)
#define FIN_BLOCKS 16

typedef __attribute__((ext_vector_type(4))) float f32x4;
typedef __attribute__((ext_vector_type(2))) long long2v;   // 16 B

__device__ __forceinline__ void async16(const unsigned char* g, unsigned char* l) {
    __builtin_amdgcn_global_load_lds(
        (const __attribute__((address_space(1))) unsigned int*)(const void*)g,
        (__attribute__((address_space(3))) unsigned int*)(void*)l,
        16, 0, 0);
}

// ---------------- Kernel 1: row-normalize + convert to fp8 e4m3 (padded K) --
// One wave per row, 8 rows/wave, butterfly reduce (no LDS/barrier).
__global__ __launch_bounds__(256) void normalize_kernel(
    const float* __restrict__ A, const float* __restrict__ P,
    unsigned char* __restrict__ Af8, unsigned char* __restrict__ Pf8,
    float* __restrict__ rowexp, float* __restrict__ rowsum, float* __restrict__ acc)
{
    const int which = blockIdx.y;
    const float* srcM = which ? P : A;
    unsigned char* dstM = which ? Pf8 : Af8;
    const int t  = threadIdx.x;
    const int wv = t >> 6;
    const int L  = t & 63;
    const int rowBase = blockIdx.x * 32 + wv * 8;

    if (which == 0) {
        const int rb = blockIdx.x * 32;
        if (t < 32) { rowexp[rb + t] = 0.0f; rowsum[rb + t] = 0.0f; }
        if (blockIdx.x == 0 && t < 4) acc[t] = 0.0f;   // acc[3] = finalize done-counter
    }

    #pragma unroll 2
    for (int j = 0; j < 8; ++j) {
        const int r = rowBase + j;
        const float2* s2 = (const float2*)(srcM + (size_t)r * D_K);

        float2 a0 = s2[2 * L];       float2 a1 = s2[2 * L + 1];       // ints 0..63
        float2 b0 = s2[2 * L + 128]; float2 b1 = s2[2 * L + 129];     // ints 64..127
        float2 c0 = {0.f, 0.f},      c1 = {0.f, 0.f};                 // ints 128..159
        if (L < 28)       { c0 = s2[2 * L + 256]; c1 = s2[2 * L + 257]; }
        else if (L == 28) { c0 = s2[312]; }                            // floats 624,625

        float ss = a0.x * a0.x + a0.y * a0.y + a1.x * a1.x + a1.y * a1.y
                 + b0.x * b0.x + b0.y * b0.y + b1.x * b1.x + b1.y * b1.y
                 + c0.x * c0.x + c0.y * c0.y + c1.x * c1.x + c1.y * c1.y;
        #pragma unroll
        for (int off = 32; off; off >>= 1) ss += __shfl_xor(ss, off, 64);
        const float rn = rsqrtf(ss);   // norms ~25, eps never active

        int* d4 = (int*)(dstM + (size_t)r * KPAD);
        int pk0 = __builtin_amdgcn_cvt_pk_fp8_f32(a0.x * rn, a0.y * rn, 0, false);
        pk0 = __builtin_amdgcn_cvt_pk_fp8_f32(a1.x * rn, a1.y * rn, pk0, true);
        d4[L] = pk0;
        int pk1 = __builtin_amdgcn_cvt_pk_fp8_f32(b0.x * rn, b0.y * rn, 0, false);
        pk1 = __builtin_amdgcn_cvt_pk_fp8_f32(b1.x * rn, b1.y * rn, pk1, true);
        d4[L + 64] = pk1;
        if (L < 32) {
            int pk2 = __builtin_amdgcn_cvt_pk_fp8_f32(c0.x * rn, c0.y * rn, 0, false);
            pk2 = __builtin_amdgcn_cvt_pk_fp8_f32(c1.x * rn, c1.y * rn, pk2, true);
            d4[L + 128] = pk2;
        }
    }
}

// ---------------- Kernel 2: fused fp8 cosine-GEMM + row reductions ----------
// R12: A fragments load DIRECTLY global->VGPR (perfectly coalesced: per
// (mi,p) instruction the wave reads 16 rows x one aligned 64-B sector).
// Only B goes through the global_load_lds double-buffer -> barrier-drained
// bytes halve (16 KB/step) and LDS drops to 32 KB/block (5 blocks/CU by LDS;
// VGPR-bound in practice). A's k-window for part p = p*64 + quad*16 = content
// chunks 4p+quad, matching B's LDS content mapping exactly -> dots unchanged.
// R10 lesson kept: no device-scope fences on this kernel's exit path.
__global__ __launch_bounds__(256) void gemm_fused_kernel(
    const unsigned char* __restrict__ Af8, const unsigned char* __restrict__ Pf8,
    float* __restrict__ rowexp, float* __restrict__ rowsum, float* __restrict__ diag)
{
    __shared__ __align__(16) unsigned char sB[2][BN * BK];   // 32 KB total

    const int t    = threadIdx.x;
    const int lane = t & 63;
    const int w    = t >> 6;
    const int wr   = w >> 1;      // wave row (0..1)
    const int wc   = w & 1;      // wave col (0..1)
    const int quad = lane >> 4;
    const int l15  = lane & 15;
    const int rx   = l15 & 7;

    const int rowBase = blockIdx.x * BM;       // 64 row-tiles
    const int chunk   = blockIdx.y;            // 16 col-chunks

    // B staging: 1024 chunks of 16 B, 4 per thread (p = t + j*256)
    const int p0 = t, p1 = t + 256, p2 = t + 512, p3 = t + 768;
    const int r0 = p0 >> 3, r1 = p1 >> 3, r2 = p2 >> 3, r3 = p3 >> 3;
    const size_t g0 = (size_t)r0 * KPAD + (size_t)(((p0 & 7) ^ (r0 & 7)) * 16);
    const size_t g1 = (size_t)r1 * KPAD + (size_t)(((p1 & 7) ^ (r1 & 7)) * 16);
    const size_t g2 = (size_t)r2 * KPAD + (size_t)(((p2 & 7) ^ (r2 & 7)) * 16);
    const size_t g3 = (size_t)r3 * KPAD + (size_t)(((p3 & 7) ^ (r3 & 7)) * 16);

    const unsigned char* PbChunk = Pf8 + (size_t)(chunk * TILES_PER_CHUNK) * BN * KPAD;

    // A fragment base pointers (per mi): row = rowBase + wr*64 + mi*16 + l15,
    // byte offset quad*16 within each 64-B part-window.
    const int aRow = wr * 64 + l15;
    const unsigned char* aP[4];
    #pragma unroll
    for (int mi = 0; mi < 4; ++mi)
        aP[mi] = Af8 + (size_t)(rowBase + aRow + mi * 16) * KPAD + quad * 16;

    // B fragment read offsets: part p -> physical chunk ((4p+quad)^rx)
    const int bRow = wc * 64 + l15;
    const int cOff0 = ((quad) ^ rx) * 16;       // part 0 (content chunk quad)
    const int cOff1 = ((4 + quad) ^ rx) * 16;   // part 1 (content chunk 4+quad)

    // persistent per-lane row partials: [mi][reg]
    float psum[4][4], pexp[4][4];
    #pragma unroll
    for (int i = 0; i < 4; ++i)
        #pragma unroll
        for (int j = 0; j < 4; ++j) { psum[i][j] = 0.0f; pexp[i][j] = 0.0f; }

    f32x4 acc[4][4];
    const f32x4 z = {0.f, 0.f, 0.f, 0.f};
    #pragma unroll
    for (int i = 0; i < 4; ++i)
        #pragma unroll
        for (int j = 0; j < 4; ++j) acc[i][j] = z;

    // prologue: stage B(ct=0, ks=0) into buffer 0
    async16(PbChunk + g0, &sB[0][p0 * 16]);
    async16(PbChunk + g1, &sB[0][p1 * 16]);
    async16(PbChunk + g2, &sB[0][p2 * 16]);
    async16(PbChunk + g3, &sB[0][p3 * 16]);

    int par = 0;   // buffer holding the CURRENT iteration's B tile
    for (int ct = 0; ct < TILES_PER_CHUNK; ++ct) {
        #pragma unroll 1
        for (int ks = 0; ks < KSTEPS; ++ks) {
            const int kOff = ks * BK;
            __syncthreads();   // buf[par] ready (loads in flight since last iter)

            // issue next iteration's B staging into buf[par^1]
            int nks = ks + 1, nct = ct;
            if (nks == KSTEPS) { nks = 0; ++nct; }
            if (nct < TILES_PER_CHUNK) {
                const int nxt = par ^ 1;
                const unsigned char* PbN =
                    PbChunk + (size_t)nct * BN * KPAD + (size_t)nks * BK;
                async16(PbN + g0, &sB[nxt][p0 * 16]);
                async16(PbN + g1, &sB[nxt][p1 * 16]);
                async16(PbN + g2, &sB[nxt][p2 * 16]);
                async16(PbN + g3, &sB[nxt][p3 * 16]);
            }

            // A fragments for this step: 8 coalesced 16-B loads (4 mi x 2 p)
            long2v aF0[4], aF1[4];
            #pragma unroll
            for (int mi = 0; mi < 4; ++mi) {
                aF0[mi] = *(const long2v*)(aP[mi] + kOff);        // part 0
                aF1[mi] = *(const long2v*)(aP[mi] + kOff + 64);   // part 1
            }

            // part 0
            {
                long2v bF[4];
                #pragma unroll
                for (int ni = 0; ni < 4; ++ni)
                    bF[ni] = *(const long2v*)&sB[par][(bRow + ni * 16) * BK + cOff0];
                #pragma unroll
                for (int half = 0; half < 2; ++half)
                    #pragma unroll
                    for (int mi = 0; mi < 4; ++mi)
                        #pragma unroll
                        for (int ni = 0; ni < 4; ++ni)
                            acc[mi][ni] = __builtin_amdgcn_mfma_f32_16x16x32_fp8_fp8(
                                aF0[mi][half], bF[ni][half], acc[mi][ni], 0, 0, 0);
            }
            // part 1
            {
                long2v bF[4];
                #pragma unroll
                for (int ni = 0; ni < 4; ++ni)
                    bF[ni] = *(const long2v*)&sB[par][(bRow + ni * 16) * BK + cOff1];
                #pragma unroll
                for (int half = 0; half < 2; ++half)
                    #pragma unroll
                    for (int mi = 0; mi < 4; ++mi)
                        #pragma unroll
                        for (int ni = 0; ni < 4; ++ni)
                            acc[mi][ni] = __builtin_amdgcn_mfma_f32_16x16x32_fp8_fp8(
                                aF1[mi][half], bF[ni][half], acc[mi][ni], 0, 0, 0);
            }
            par ^= 1;
        }

        // ----- per-ct epilogue (registers only, no LDS -> no barrier) -----
        const int colBase = (chunk * TILES_PER_CHUNK + ct) * BN;

        if (rowBase == colBase && wr == wc) {   // diagonal tile: rare, uniform
            #pragma unroll
            for (int mi = 0; mi < 4; ++mi)
                #pragma unroll
                for (int r = 0; r < 4; ++r)
                    if (l15 == quad * 4 + r)
                        diag[rowBase + wr * 64 + mi * 16 + l15] = acc[mi][mi][r];
        }

        // C/D layout col = l15, row = quad*4 + reg
        #pragma unroll
        for (int mi = 0; mi < 4; ++mi) {
            #pragma unroll
            for (int r = 0; r < 4; ++r) {
                float s4 = 0.f, e4 = 0.f;
                #pragma unroll
                for (int ni = 0; ni < 4; ++ni) {
                    const float S = acc[mi][ni][r];
                    s4 += S;
                    e4 += __expf(S * 4.0f);        // logits = S / 0.25
                }
                psum[mi][r] += s4;
                pexp[mi][r] += e4;
            }
        }
        #pragma unroll
        for (int i = 0; i < 4; ++i)
            #pragma unroll
            for (int j = 0; j < 4; ++j) acc[i][j] = z;
    }

    // reduce across the 16 columns (l15 lanes) of each quad-group
    #pragma unroll
    for (int off = 1; off <= 8; off <<= 1) {
        #pragma unroll
        for (int mi = 0; mi < 4; ++mi)
            #pragma unroll
            for (int r = 0; r < 4; ++r) {
                psum[mi][r] += __shfl_xor(psum[mi][r], off, 64);
                pexp[mi][r] += __shfl_xor(pexp[mi][r], off, 64);
            }
    }
    if (l15 == 0) {
        #pragma unroll
        for (int mi = 0; mi < 4; ++mi)
            #pragma unroll
            for (int r = 0; r < 4; ++r) {
                const int gr = rowBase + wr * 64 + mi * 16 + quad * 4 + r;
                atomicAdd(&rowsum[gr], psum[mi][r]);
                atomicAdd(&rowexp[gr], pexp[mi][r]);
            }
    }
}

// ---------------- Kernel 3: final reduction + device-side completion --------
__global__ __launch_bounds__(256) void finalize_kernel(
    const float* __restrict__ rowexp, const float* __restrict__ rowsum,
    const float* __restrict__ diag, float* __restrict__ acc, float* __restrict__ out)
{
    const int t = threadIdx.x;
    float ls = 0.f, ds = 0.f, ns = 0.f;
    for (int i = blockIdx.x * 256 + t; i < B_N; i += FIN_BLOCKS * 256) {
        const float d = diag[i];
        ls += __logf(rowexp[i]) - d * 4.0f;   // logsumexp - diag_logit
        ds += d;
        ns += (rowsum[i] - d);
    }
    #pragma unroll
    for (int off = 32; off; off >>= 1) {
        ls += __shfl_down(ls, off, 64);
        ds += __shfl_down(ds, off, 64);
        ns += __shfl_down(ns, off, 64);
    }
    __shared__ float sl[4], sd[4], sn[4];
    if ((t & 63) == 0) { sl[t >> 6] = ls; sd[t >> 6] = ds; sn[t >> 6] = ns; }
    __syncthreads();
    if (t == 0) {
        atomicAdd(acc + 0, sl[0] + sl[1] + sl[2] + sl[3]);
        atomicAdd(acc + 1, sd[0] + sd[1] + sd[2] + sd[3]);
        atomicAdd(acc + 2, sn[0] + sn[1] + sn[2] + sn[3]);
        __threadfence();
        const int done = (int)atomicAdd((unsigned int*)(acc + 3), 1u);
        if (done == FIN_BLOCKS - 1) {
            const float L  = atomicAdd(acc + 0, 0.0f);   // coherent reads
            const float Dm = atomicAdd(acc + 1, 0.0f);
            const float Nn = atomicAdd(acc + 2, 0.0f);
            out[0] = L / (float)B_N;
            out[1] = Dm / (float)B_N;
            out[2] = (Nn / (float)(B_N - 1)) / (float)B_N;
        }
    }
}

// ---------------- Fallback path (small workspace): fp32 vector --------------
__global__ __launch_bounds__(256) void fb_norm(
    const float* __restrict__ A, const float* __restrict__ P,
    float* __restrict__ rna, float* __restrict__ rnp, float* __restrict__ acc)
{
    const int r = blockIdx.x;
    const float* src = blockIdx.y ? P : A;
    const int t = threadIdx.x;
    float ss = 0.f;
    for (int k = t; k < D_K; k += 256) { float v = src[(size_t)r * D_K + k]; ss += v * v; }
    #pragma unroll
    for (int off = 32; off; off >>= 1) ss += __shfl_down(ss, off, 64);
    __shared__ float sred[4];
    if ((t & 63) == 0) sred[t >> 6] = ss;
    __syncthreads();
    if (t == 0) {
        const float rn = rsqrtf(sred[0] + sred[1] + sred[2] + sred[3]);
        (blockIdx.y ? rnp : rna)[r] = rn;
    }
    if (blockIdx.x == 0 && blockIdx.y == 0 && t < 3) acc[t] = 0.0f;
}

__global__ __launch_bounds__(256) void fb_main(
    const float* __restrict__ A, const float* __restrict__ P,
    const float* __restrict__ rna, const float* __restrict__ rnp,
    float* __restrict__ acc)
{
    __shared__ float sa[D_K];
    __shared__ float red[12];
    const int i = blockIdx.x;
    const int t = threadIdx.x;
    const float rn = rna[i];
    for (int k = t; k < D_K; k += 256) sa[k] = A[(size_t)i * D_K + k] * rn;
    __syncthreads();
    const int w = t >> 6, lane = t & 63;
    float we = 0.f, wsum = 0.f, wd = 0.f;
    for (int j = w; j < B_N; j += 4) {
        float dot = 0.f;
        const float* p = P + (size_t)j * D_K;
        for (int k = lane; k < D_K; k += 64) dot += sa[k] * p[k];
        #pragma unroll
        for (int off = 32; off; off >>= 1) dot += __shfl_xor(dot, off, 64);
        const float S = dot * rnp[j];
        we += __expf(S * 4.0f);
        wsum += S;
        if (j == i) wd = S;
    }
    if (lane == 0) { red[w] = we; red[4 + w] = wsum; red[8 + w] = wd; }
    __syncthreads();
    if (t == 0) {
        const float E  = red[0] + red[1] + red[2] + red[3];
        const float Sm = red[4] + red[5] + red[6] + red[7];
        const float Dd = red[8] + red[9] + red[10] + red[11];
        atomicAdd(acc + 0, __logf(E) - 4.0f * Dd);
        atomicAdd(acc + 1, Dd);
        atomicAdd(acc + 2, Sm - Dd);
    }
}

__global__ void fb_fin(const float* __restrict__ acc, float* __restrict__ out)
{
    out[0] = acc[0] / (float)B_N;
    out[1] = acc[1] / (float)B_N;
    out[2] = acc[2] / ((float)(B_N - 1) * (float)B_N);
}

// ---------------------------------------------------------------------------
extern "C" void kernel_launch(void* const* d_in, const int* in_sizes, int n_in,
                              void* d_out, int out_size, void* d_ws, size_t ws_size,
                              hipStream_t stream)
{
    const float* A = (const float*)d_in[0];
    const float* P = (const float*)d_in[1];
    float* out = (float*)d_out;
    char* ws = (char*)d_ws;

    const size_t AF8_OFF  = 0;
    const size_t PF8_OFF  = AF8_OFF + (size_t)B_N * KPAD;
    const size_t REXP_OFF = PF8_OFF + (size_t)B_N * KPAD;
    const size_t RSUM_OFF = REXP_OFF + (size_t)B_N * sizeof(float);
    const size_t DIAG_OFF = RSUM_OFF + (size_t)B_N * sizeof(float);
    const size_t ACC_OFF  = DIAG_OFF + (size_t)B_N * sizeof(float);
    const size_t MAIN_REQ = ACC_OFF + 16;

    if (ws_size >= MAIN_REQ) {
        unsigned char* Af8 = (unsigned char*)(ws + AF8_OFF);
        unsigned char* Pf8 = (unsigned char*)(ws + PF8_OFF);
        float* rowexp = (float*)(ws + REXP_OFF);
        float* rowsum = (float*)(ws + RSUM_OFF);
        float* diag   = (float*)(ws + DIAG_OFF);
        float* acc    = (float*)(ws + ACC_OFF);

        normalize_kernel<<<dim3(B_N / 32, 2), 256, 0, stream>>>(A, P, Af8, Pf8,
                                                                rowexp, rowsum, acc);
        gemm_fused_kernel<<<dim3(B_N / BM, COL_CHUNKS), 256, 0, stream>>>(
            Af8, Pf8, rowexp, rowsum, diag);
        finalize_kernel<<<FIN_BLOCKS, 256, 0, stream>>>(rowexp, rowsum, diag, acc, out);
    } else {
        // slow-but-correct fp32 fallback (needs ~96 KB ws)
        float* rna = (float*)ws;
        float* rnp = rna + B_N;
        float* acc = rnp + B_N;
        fb_norm<<<dim3(B_N, 2), 256, 0, stream>>>(A, P, rna, rnp, acc);
        fb_main<<<B_N, 256, 0, stream>>>(A, P, rna, rnp, acc);
        fb_fin<<<1, 1, 0, stream>>>(acc, out);
    }
}

// Round 13
// 156.427 us; speedup vs baseline: 1.5678x; 1.5678x over previous
//
#include <hip/hip_runtime.h>
#include <stdint.h>

#define B_N   8192
#define D_K   626
#define KPAD  640        // fp8 bytes per row (padded)
#define BK    128        // K-bytes per step (R6-validated optimum)
#define KSTEPS 5         // KPAD / BK
#define BM    128
#define BN    128
#define COL_CHUNKS 16
#define TILES_PER_CHUNK 4   // 8192 / (16*128)
#define FIN_BLOCKS 16

typedef __attribute__((ext_vector_type(4))) float f32x4;
typedef __attribute__((ext_vector_type(2))) long long2v;   // 16 B = one LDS chunk

__device__ __forceinline__ void async16(const unsigned char* g, unsigned char* l) {
    __builtin_amdgcn_global_load_lds(
        (const __attribute__((address_space(1))) unsigned int*)(const void*)g,
        (__attribute__((address_space(3))) unsigned int*)(void*)l,
        16, 0, 0);
}

// ---------------- Kernel 1: row-normalize + convert to fp8 e4m3 (padded K) --
// One wave per row, 8 rows/wave, butterfly reduce (no LDS/barrier).
__global__ __launch_bounds__(256) void normalize_kernel(
    const float* __restrict__ A, const float* __restrict__ P,
    unsigned char* __restrict__ Af8, unsigned char* __restrict__ Pf8,
    float* __restrict__ rowexp, float* __restrict__ rowsum, float* __restrict__ acc)
{
    const int which = blockIdx.y;
    const float* srcM = which ? P : A;
    unsigned char* dstM = which ? Pf8 : Af8;
    const int t  = threadIdx.x;
    const int wv = t >> 6;
    const int L  = t & 63;
    const int rowBase = blockIdx.x * 32 + wv * 8;

    if (which == 0) {
        const int rb = blockIdx.x * 32;
        if (t < 32) { rowexp[rb + t] = 0.0f; rowsum[rb + t] = 0.0f; }
        if (blockIdx.x == 0 && t < 4) acc[t] = 0.0f;   // acc[3] = finalize done-counter
    }

    #pragma unroll 2
    for (int j = 0; j < 8; ++j) {
        const int r = rowBase + j;
        const float2* s2 = (const float2*)(srcM + (size_t)r * D_K);

        float2 a0 = s2[2 * L];       float2 a1 = s2[2 * L + 1];       // ints 0..63
        float2 b0 = s2[2 * L + 128]; float2 b1 = s2[2 * L + 129];     // ints 64..127
        float2 c0 = {0.f, 0.f},      c1 = {0.f, 0.f};                 // ints 128..159
        if (L < 28)       { c0 = s2[2 * L + 256]; c1 = s2[2 * L + 257]; }
        else if (L == 28) { c0 = s2[312]; }                            // floats 624,625

        float ss = a0.x * a0.x + a0.y * a0.y + a1.x * a1.x + a1.y * a1.y
                 + b0.x * b0.x + b0.y * b0.y + b1.x * b1.x + b1.y * b1.y
                 + c0.x * c0.x + c0.y * c0.y + c1.x * c1.x + c1.y * c1.y;
        #pragma unroll
        for (int off = 32; off; off >>= 1) ss += __shfl_xor(ss, off, 64);
        const float rn = rsqrtf(ss);   // norms ~25, eps never active

        int* d4 = (int*)(dstM + (size_t)r * KPAD);
        int pk0 = __builtin_amdgcn_cvt_pk_fp8_f32(a0.x * rn, a0.y * rn, 0, false);
        pk0 = __builtin_amdgcn_cvt_pk_fp8_f32(a1.x * rn, a1.y * rn, pk0, true);
        d4[L] = pk0;
        int pk1 = __builtin_amdgcn_cvt_pk_fp8_f32(b0.x * rn, b0.y * rn, 0, false);
        pk1 = __builtin_amdgcn_cvt_pk_fp8_f32(b1.x * rn, b1.y * rn, pk1, true);
        d4[L + 64] = pk1;
        if (L < 32) {
            int pk2 = __builtin_amdgcn_cvt_pk_fp8_f32(c0.x * rn, c0.y * rn, 0, false);
            pk2 = __builtin_amdgcn_cvt_pk_fp8_f32(c1.x * rn, c1.y * rn, pk2, true);
            d4[L + 128] = pk2;
        }
    }
}

// ---------------- Kernel 2: fused fp8 cosine-GEMM + row reductions ----------
// FROZEN R6/R11 structure (measured 81.3-84.7 us across four runs,
// MfmaUtil ~42%, 0 bank conflicts, no spill):
// BK=128 double-buffer, ONE barrier per K-step, launch_bounds(256,2).
// Survived-experiment ledger (do NOT retry):
//  - R8: min-waves=4 -> forced 64 VGPR -> 181 MB scratch spill (2x slower)
//  - R9: BK=64 -> halves per-barrier latency budget (2x slower)
//  - R10: fused exit-path __threadfence -> L2 writeback storm (2x slower)
//  - R12: A direct global->VGPR -> in-order vmcnt drains the B prefetch
//    at first A use (2x slower)
__global__ __launch_bounds__(256, 2) void gemm_fused_kernel(
    const unsigned char* __restrict__ Af8, const unsigned char* __restrict__ Pf8,
    float* __restrict__ rowexp, float* __restrict__ rowsum, float* __restrict__ diag)
{
    __shared__ __align__(16) unsigned char sA[2][BM * BK];   // 32 KB
    __shared__ __align__(16) unsigned char sB[2][BN * BK];   // 32 KB

    const int t    = threadIdx.x;
    const int lane = t & 63;
    const int w    = t >> 6;
    const int wr   = w >> 1;      // wave row (0..1)
    const int wc   = w & 1;       // wave col (0..1)
    const int quad = lane >> 4;
    const int l15  = lane & 15;
    const int rx   = l15 & 7;

    const int rowBase = blockIdx.x * BM;       // 64 row-tiles
    const int chunk   = blockIdx.y;            // 16 col-chunks

    // staging: per matrix 1024 chunks of 16 B, 4 per thread (p = t + j*256)
    const int p0 = t, p1 = t + 256, p2 = t + 512, p3 = t + 768;
    const int r0 = p0 >> 3, r1 = p1 >> 3, r2 = p2 >> 3, r3 = p3 >> 3;
    const size_t g0 = (size_t)r0 * KPAD + (size_t)(((p0 & 7) ^ (r0 & 7)) * 16);
    const size_t g1 = (size_t)r1 * KPAD + (size_t)(((p1 & 7) ^ (r1 & 7)) * 16);
    const size_t g2 = (size_t)r2 * KPAD + (size_t)(((p2 & 7) ^ (r2 & 7)) * 16);
    const size_t g3 = (size_t)r3 * KPAD + (size_t)(((p3 & 7) ^ (r3 & 7)) * 16);

    const unsigned char* Ab = Af8 + (size_t)rowBase * KPAD;
    const unsigned char* PbChunk = Pf8 + (size_t)(chunk * TILES_PER_CHUNK) * BN * KPAD;

    // fragment read offsets: part p -> physical chunk ((4p+quad)^rx)
    const int aRow = wr * 64 + l15;
    const int bRow = wc * 64 + l15;
    const int cOff0 = ((quad) ^ rx) * 16;       // part 0
    const int cOff1 = ((4 + quad) ^ rx) * 16;   // part 1

    // persistent per-lane row partials: [mi][reg]
    float psum[4][4], pexp[4][4];
    #pragma unroll
    for (int i = 0; i < 4; ++i)
        #pragma unroll
        for (int j = 0; j < 4; ++j) { psum[i][j] = 0.0f; pexp[i][j] = 0.0f; }

    f32x4 acc[4][4];
    const f32x4 z = {0.f, 0.f, 0.f, 0.f};
    #pragma unroll
    for (int i = 0; i < 4; ++i)
        #pragma unroll
        for (int j = 0; j < 4; ++j) acc[i][j] = z;

    // prologue: stage (ct=0, ks=0) into buffer 0
    {
        async16(Ab + g0, &sA[0][p0 * 16]);
        async16(Ab + g1, &sA[0][p1 * 16]);
        async16(Ab + g2, &sA[0][p2 * 16]);
        async16(Ab + g3, &sA[0][p3 * 16]);
        async16(PbChunk + g0, &sB[0][p0 * 16]);
        async16(PbChunk + g1, &sB[0][p1 * 16]);
        async16(PbChunk + g2, &sB[0][p2 * 16]);
        async16(PbChunk + g3, &sB[0][p3 * 16]);
    }

    int par = 0;   // buffer holding the CURRENT iteration's tiles
    for (int ct = 0; ct < TILES_PER_CHUNK; ++ct) {
        #pragma unroll 1
        for (int ks = 0; ks < KSTEPS; ++ks) {
            __syncthreads();   // buf[par] ready (loads in flight since last iter)

            // issue next iteration's staging into buf[par^1]
            int nks = ks + 1, nct = ct;
            if (nks == KSTEPS) { nks = 0; ++nct; }
            if (nct < TILES_PER_CHUNK) {
                const int nxt = par ^ 1;
                const size_t nkOff = (size_t)nks * BK;
                const unsigned char* PbN = PbChunk + (size_t)nct * BN * KPAD + nkOff;
                const unsigned char* AbN = Ab + nkOff;
                async16(AbN + g0, &sA[nxt][p0 * 16]);
                async16(AbN + g1, &sA[nxt][p1 * 16]);
                async16(AbN + g2, &sA[nxt][p2 * 16]);
                async16(AbN + g3, &sA[nxt][p3 * 16]);
                async16(PbN + g0, &sB[nxt][p0 * 16]);
                async16(PbN + g1, &sB[nxt][p1 * 16]);
                async16(PbN + g2, &sB[nxt][p2 * 16]);
                async16(PbN + g3, &sB[nxt][p3 * 16]);
            }

            // compute from buf[par]
            #pragma unroll
            for (int p = 0; p < 2; ++p) {
                const int cOff = p ? cOff1 : cOff0;
                long2v aF[4], bF[4];
                #pragma unroll
                for (int mi = 0; mi < 4; ++mi)
                    aF[mi] = *(const long2v*)&sA[par][(aRow + mi * 16) * BK + cOff];
                #pragma unroll
                for (int ni = 0; ni < 4; ++ni)
                    bF[ni] = *(const long2v*)&sB[par][(bRow + ni * 16) * BK + cOff];

                #pragma unroll
                for (int half = 0; half < 2; ++half)
                    #pragma unroll
                    for (int mi = 0; mi < 4; ++mi)
                        #pragma unroll
                        for (int ni = 0; ni < 4; ++ni)
                            acc[mi][ni] = __builtin_amdgcn_mfma_f32_16x16x32_fp8_fp8(
                                aF[mi][half], bF[ni][half], acc[mi][ni], 0, 0, 0);
            }
            par ^= 1;
        }

        // ----- per-ct epilogue (registers only, no LDS -> no barrier) -----
        const int colBase = (chunk * TILES_PER_CHUNK + ct) * BN;

        if (rowBase == colBase && wr == wc) {   // diagonal tile: rare, uniform
            #pragma unroll
            for (int mi = 0; mi < 4; ++mi)
                #pragma unroll
                for (int r = 0; r < 4; ++r)
                    if (l15 == quad * 4 + r)
                        diag[rowBase + wr * 64 + mi * 16 + l15] = acc[mi][mi][r];
        }

        // C/D layout col = l15, row = quad*4 + reg
        #pragma unroll
        for (int mi = 0; mi < 4; ++mi) {
            #pragma unroll
            for (int r = 0; r < 4; ++r) {
                float s4 = 0.f, e4 = 0.f;
                #pragma unroll
                for (int ni = 0; ni < 4; ++ni) {
                    const float S = acc[mi][ni][r];
                    s4 += S;
                    e4 += __expf(S * 4.0f);        // logits = S / 0.25
                }
                psum[mi][r] += s4;
                pexp[mi][r] += e4;
            }
        }
        #pragma unroll
        for (int i = 0; i < 4; ++i)
            #pragma unroll
            for (int j = 0; j < 4; ++j) acc[i][j] = z;
    }

    // reduce across the 16 columns (l15 lanes) of each quad-group
    #pragma unroll
    for (int off = 1; off <= 8; off <<= 1) {
        #pragma unroll
        for (int mi = 0; mi < 4; ++mi)
            #pragma unroll
            for (int r = 0; r < 4; ++r) {
                psum[mi][r] += __shfl_xor(psum[mi][r], off, 64);
                pexp[mi][r] += __shfl_xor(pexp[mi][r], off, 64);
            }
    }
    if (l15 == 0) {
        #pragma unroll
        for (int mi = 0; mi < 4; ++mi)
            #pragma unroll
            for (int r = 0; r < 4; ++r) {
                const int gr = rowBase + wr * 64 + mi * 16 + quad * 4 + r;
                atomicAdd(&rowsum[gr], psum[mi][r]);
                atomicAdd(&rowexp[gr], pexp[mi][r]);
            }
    }
}

// ---------------- Kernel 3: final reduction + device-side completion --------
__global__ __launch_bounds__(256) void finalize_kernel(
    const float* __restrict__ rowexp, const float* __restrict__ rowsum,
    const float* __restrict__ diag, float* __restrict__ acc, float* __restrict__ out)
{
    const int t = threadIdx.x;
    float ls = 0.f, ds = 0.f, ns = 0.f;
    for (int i = blockIdx.x * 256 + t; i < B_N; i += FIN_BLOCKS * 256) {
        const float d = diag[i];
        ls += __logf(rowexp[i]) - d * 4.0f;   // logsumexp - diag_logit
        ds += d;
        ns += (rowsum[i] - d);
    }
    #pragma unroll
    for (int off = 32; off; off >>= 1) {
        ls += __shfl_down(ls, off, 64);
        ds += __shfl_down(ds, off, 64);
        ns += __shfl_down(ns, off, 64);
    }
    __shared__ float sl[4], sd[4], sn[4];
    if ((t & 63) == 0) { sl[t >> 6] = ls; sd[t >> 6] = ds; sn[t >> 6] = ns; }
    __syncthreads();
    if (t == 0) {
        atomicAdd(acc + 0, sl[0] + sl[1] + sl[2] + sl[3]);
        atomicAdd(acc + 1, sd[0] + sd[1] + sd[2] + sd[3]);
        atomicAdd(acc + 2, sn[0] + sn[1] + sn[2] + sn[3]);
        __threadfence();
        const int done = (int)atomicAdd((unsigned int*)(acc + 3), 1u);
        if (done == FIN_BLOCKS - 1) {
            const float L  = atomicAdd(acc + 0, 0.0f);   // coherent reads
            const float Dm = atomicAdd(acc + 1, 0.0f);
            const float Nn = atomicAdd(acc + 2, 0.0f);
            out[0] = L / (float)B_N;
            out[1] = Dm / (float)B_N;
            out[2] = (Nn / (float)(B_N - 1)) / (float)B_N;
        }
    }
}

// ---------------- Fallback path (small workspace): fp32 vector --------------
__global__ __launch_bounds__(256) void fb_norm(
    const float* __restrict__ A, const float* __restrict__ P,
    float* __restrict__ rna, float* __restrict__ rnp, float* __restrict__ acc)
{
    const int r = blockIdx.x;
    const float* src = blockIdx.y ? P : A;
    const int t = threadIdx.x;
    float ss = 0.f;
    for (int k = t; k < D_K; k += 256) { float v = src[(size_t)r * D_K + k]; ss += v * v; }
    #pragma unroll
    for (int off = 32; off; off >>= 1) ss += __shfl_down(ss, off, 64);
    __shared__ float sred[4];
    if ((t & 63) == 0) sred[t >> 6] = ss;
    __syncthreads();
    if (t == 0) {
        const float rn = rsqrtf(sred[0] + sred[1] + sred[2] + sred[3]);
        (blockIdx.y ? rnp : rna)[r] = rn;
    }
    if (blockIdx.x == 0 && blockIdx.y == 0 && t < 3) acc[t] = 0.0f;
}

__global__ __launch_bounds__(256) void fb_main(
    const float* __restrict__ A, const float* __restrict__ P,
    const float* __restrict__ rna, const float* __restrict__ rnp,
    float* __restrict__ acc)
{
    __shared__ float sa[D_K];
    __shared__ float red[12];
    const int i = blockIdx.x;
    const int t = threadIdx.x;
    const float rn = rna[i];
    for (int k = t; k < D_K; k += 256) sa[k] = A[(size_t)i * D_K + k] * rn;
    __syncthreads();
    const int w = t >> 6, lane = t & 63;
    float we = 0.f, wsum = 0.f, wd = 0.f;
    for (int j = w; j < B_N; j += 4) {
        float dot = 0.f;
        const float* p = P + (size_t)j * D_K;
        for (int k = lane; k < D_K; k += 64) dot += sa[k] * p[k];
        #pragma unroll
        for (int off = 32; off; off >>= 1) dot += __shfl_xor(dot, off, 64);
        const float S = dot * rnp[j];
        we += __expf(S * 4.0f);
        wsum += S;
        if (j == i) wd = S;
    }
    if (lane == 0) { red[w] = we; red[4 + w] = wsum; red[8 + w] = wd; }
    __syncthreads();
    if (t == 0) {
        const float E  = red[0] + red[1] + red[2] + red[3];
        const float Sm = red[4] + red[5] + red[6] + red[7];
        const float Dd = red[8] + red[9] + red[10] + red[11];
        atomicAdd(acc + 0, __logf(E) - 4.0f * Dd);
        atomicAdd(acc + 1, Dd);
        atomicAdd(acc + 2, Sm - Dd);
    }
}

__global__ void fb_fin(const float* __restrict__ acc, float* __restrict__ out)
{
    out[0] = acc[0] / (float)B_N;
    out[1] = acc[1] / (float)B_N;
    out[2] = acc[2] / ((float)(B_N - 1) * (float)B_N);
}

// ---------------------------------------------------------------------------
extern "C" void kernel_launch(void* const* d_in, const int* in_sizes, int n_in,
                              void* d_out, int out_size, void* d_ws, size_t ws_size,
                              hipStream_t stream)
{
    const float* A = (const float*)d_in[0];
    const float* P = (const float*)d_in[1];
    float* out = (float*)d_out;
    char* ws = (char*)d_ws;

    const size_t AF8_OFF  = 0;
    const size_t PF8_OFF  = AF8_OFF + (size_t)B_N * KPAD;
    const size_t REXP_OFF = PF8_OFF + (size_t)B_N * KPAD;
    const size_t RSUM_OFF = REXP_OFF + (size_t)B_N * sizeof(float);
    const size_t DIAG_OFF = RSUM_OFF + (size_t)B_N * sizeof(float);
    const size_t ACC_OFF  = DIAG_OFF + (size_t)B_N * sizeof(float);
    const size_t MAIN_REQ = ACC_OFF + 16;

    if (ws_size >= MAIN_REQ) {
        unsigned char* Af8 = (unsigned char*)(ws + AF8_OFF);
        unsigned char* Pf8 = (unsigned char*)(ws + PF8_OFF);
        float* rowexp = (float*)(ws + REXP_OFF);
        float* rowsum = (float*)(ws + RSUM_OFF);
        float* diag   = (float*)(ws + DIAG_OFF);
        float* acc    = (float*)(ws + ACC_OFF);

        normalize_kernel<<<dim3(B_N / 32, 2), 256, 0, stream>>>(A, P, Af8, Pf8,
                                                                rowexp, rowsum, acc);
        gemm_fused_kernel<<<dim3(B_N / BM, COL_CHUNKS), 256, 0, stream>>>(
            Af8, Pf8, rowexp, rowsum, diag);
        finalize_kernel<<<FIN_BLOCKS, 256, 0, stream>>>(rowexp, rowsum, diag, acc, out);
    } else {
        // slow-but-correct fp32 fallback (needs ~96 KB ws)
        float* rna = (float*)ws;
        float* rnp = rna + B_N;
        float* acc = rnp + B_N;
        fb_norm<<<dim3(B_N, 2), 256, 0, stream>>>(A, P, rna, rnp, acc);
        fb_main<<<B_N, 256, 0, stream>>>(A, P, rna, rnp, acc);
        fb_fin<<<1, 1, 0, stream>>>(acc, out);
    }
}